// Round 17
// baseline (1031.131 us; speedup 1.0000x reference)
//
#include <hip/hip_runtime.h>
#include <hip/hip_fp16.h>
#include <cmath>

#define NN 100000
#define EE 1600000
#define INC 500
#define HIDC 128
#define OUTC 64
#define NLAYER 8
#define NB16 6250           // NN / 16 exactly
#define NPX 12500           // NN / 8 (nodes per XCD bucket)
#define CNT_BLKS 50000      // 6250 chunks * 8 buckets
#define NBLK 391            // ceil(NN/256)
#define PERMSZ (NBLK * 256) // 100096

typedef float f32x4 __attribute__((ext_vector_type(4)));
typedef _Float16 f16x8 __attribute__((ext_vector_type(8)));
typedef short s16x8 __attribute__((ext_vector_type(8)));

// frag layout addr for (row, k), K pitch Kp: [(row/16)][k/8][row%16][k%8]
__device__ __forceinline__ int fraddr(int row, int k, int Kp) {
  return (row >> 4) * (Kp * 16) + (k >> 3) * 128 + (row & 15) * 8 + (k & 7);
}

// ---------------- graph preprocessing ----------------

// XCD-bucketed degree count: block's XCD (bid%8) == dst bucket
__global__ void __launch_bounds__(256) k_count_x(
    const int* __restrict__ dst, int* __restrict__ deg) {
  int chunk = blockIdx.x >> 3;
  int xcd = blockIdx.x & 7;
  int e = chunk * 256 + threadIdx.x;   // EE == 6250*256 exactly
  int d = dst[e];
  if (d / NPX == xcd) atomicAdd(&deg[d], 1);
}

__global__ void k_scan_block_sums(const int* __restrict__ deg, int* __restrict__ bsum, int n) {
  __shared__ int sm[256];
  int i = blockIdx.x * 256 + threadIdx.x;
  int v = (i < n) ? deg[i] + 1 : 0;  // +1 for self-loop
  sm[threadIdx.x] = v;
  __syncthreads();
  for (int s = 128; s > 0; s >>= 1) {
    if (threadIdx.x < s) sm[threadIdx.x] += sm[threadIdx.x + s];
    __syncthreads();
  }
  if (threadIdx.x == 0) bsum[blockIdx.x] = sm[0];
}

__global__ void k_scan_partials(int* __restrict__ bsum, int nb) {
  __shared__ int sm[512];
  int t = threadIdx.x;
  sm[t] = (t < nb) ? bsum[t] : 0;
  __syncthreads();
  for (int s = 1; s < 512; s <<= 1) {
    int v = (t >= s) ? sm[t - s] : 0;
    __syncthreads();
    sm[t] += v;
    __syncthreads();
  }
  if (t < nb) bsum[t] = (t == 0) ? 0 : sm[t - 1];  // exclusive
}

__global__ void k_scan_final(const int* __restrict__ deg, const int* __restrict__ bsum,
                             int* __restrict__ row_ptr, int n) {
  __shared__ int sm[256];
  int i = blockIdx.x * 256 + threadIdx.x;
  int v = (i < n) ? deg[i] + 1 : 0;
  sm[threadIdx.x] = v;
  __syncthreads();
  for (int s = 1; s < 256; s <<= 1) {
    int u = (threadIdx.x >= s) ? sm[threadIdx.x - s] : 0;
    __syncthreads();
    sm[threadIdx.x] += u;
    __syncthreads();
  }
  if (i < n) row_ptr[i] = bsum[blockIdx.x] + sm[threadIdx.x] - v;  // exclusive
}

__global__ void k_init_rows(const int* __restrict__ deg, const int* __restrict__ row_ptr,
                            int* __restrict__ cursor, int* __restrict__ col,
                            float* __restrict__ dinv, int n) {
  int i = blockIdx.x * blockDim.x + threadIdx.x;
  if (i < n) {
    int rp = row_ptr[i];
    col[rp] = i;          // self-loop entry first (deterministic)
    cursor[i] = rp + 1;
    dinv[i] = rsqrtf((float)(deg[i] + 1));
  }
}

// ---- per-256-node-window degree sort (deterministic LDS bitonic, no atomics) ----
// perm[base..base+255] lists the window's nodes in ascending degree order.

__global__ void __launch_bounds__(256) k_sort_win(
    const int* __restrict__ deg, int* __restrict__ perm) {
  __shared__ unsigned key[256];
  int t = threadIdx.x;
  int base = blockIdx.x * 256;
  int node = base + t;
  key[t] = (node < NN) ? (((unsigned)deg[node] << 18) | (unsigned)t) : 0xFFFFFFFFu;
  __syncthreads();
  for (int sz = 2; sz <= 256; sz <<= 1) {
    for (int st = sz >> 1; st > 0; st >>= 1) {
      int p = t ^ st;
      if (p > t) {
        unsigned a = key[t], b = key[p];
        bool asc = ((t & sz) == 0);
        if (asc ? (a > b) : (a < b)) { key[t] = b; key[p] = a; }
      }
      __syncthreads();
    }
  }
  perm[base + t] = base + (int)(key[t] & 0x3FFFFu);
}

// XCD-bucketed CSR fill
__global__ void __launch_bounds__(256) k_fill_x(
    const int* __restrict__ src, const int* __restrict__ dst,
    int* __restrict__ cursor, int* __restrict__ col) {
  int chunk = blockIdx.x >> 3;
  int xcd = blockIdx.x & 7;
  int e = chunk * 256 + threadIdx.x;   // EE == 6250*256 exactly
  int d = dst[e];
  if (d / NPX == xcd) {
    int pos = atomicAdd(&cursor[d], 1);
    col[pos] = src[e];
  }
}

// ---- W_in -> fp16 fragment layout, Kp=512 (zero-padded K>=500) ----

__global__ void k_prep_wfin16(const float* __restrict__ W, __half* __restrict__ f) {
  int i = blockIdx.x * 256 + threadIdx.x;
  if (i >= HIDC * 512) return;
  int n = i / 512, k = i % 512;
  float v = (k < INC) ? W[(size_t)k * HIDC + n] : 0.f;
  f[fraddr(n, k, 512)] = __float2half(v);
}

// ---- W -> fp16 fragment layout, optional identity fold: M = idc*I + ws*W ----

__global__ void k_prep_wf16(const float* __restrict__ W, __half* __restrict__ f,
                            int K, int N, float idc, float ws) {
  int i = blockIdx.x * 256 + threadIdx.x;
  if (i >= N * K) return;
  int n = i / K, k = i % K;
  float v = ws * W[(size_t)k * N + n] + ((k == n) ? idc : 0.f);
  f[fraddr(n, k, K)] = __float2half(v);
}

// ---------------- fp16 input GEMM, barrier-free, B-first load order ----------------
// Per K-iteration: issue 8 B-loads (L2), THEN the A-prefetch (HBM, newest),
// then MFMAs -> compiler waits count only the B-loads; A rides across iterations.

__global__ void __launch_bounds__(256) k_gemm_in(
    const float* __restrict__ A, const __half* __restrict__ Bf,
    const float* __restrict__ bias,
    __half* __restrict__ C16u, __half* __restrict__ C16s,
    const float* __restrict__ dinv) {
  int wv = threadIdx.x >> 6, lane = threadIdx.x & 63;
  int lr = lane & 15, kg = lane >> 4;
  int w16 = blockIdx.x * 4 + wv;
  if (w16 >= NB16) return;
  int row = w16 * 16 + lr;            // < NN (NN == NB16*16)

  f32x4 acc[8];
#pragma unroll
  for (int n = 0; n < 8; ++n) acc[n] = {0.f, 0.f, 0.f, 0.f};

  const float* Ar = A + (size_t)row * INC;
  const __half* Bb = Bf + lr * 8;

  float4 pa0[4], pa1[4];   // 4-deep prefetch ring (static indexing via full unroll)

  auto loadA = [&](int kt, float4& d0, float4& d1) {
    int k0 = kt * 32 + kg * 8;
    if (kt < 15 || kg < 2) {
      d0 = *reinterpret_cast<const float4*>(Ar + k0);
      d1 = *reinterpret_cast<const float4*>(Ar + k0 + 4);
    } else {              // tail: predicate (avoids OOB read past end of A)
      float t[8];
#pragma unroll
      for (int e = 0; e < 8; ++e) t[e] = (k0 + e < INC) ? Ar[k0 + e] : 0.f;
      d0 = make_float4(t[0], t[1], t[2], t[3]);
      d1 = make_float4(t[4], t[5], t[6], t[7]);
    }
  };

#pragma unroll
  for (int d = 0; d < 4; ++d) loadA(d, pa0[d], pa1[d]);

#pragma unroll
  for (int kt = 0; kt < 16; ++kt) {
    int kslab = (kt * 4 + kg) * 128;
    f16x8 bfr[8];                      // issue B first (oldest in queue)
#pragma unroll
    for (int n = 0; n < 8; ++n)
      bfr[n] = *reinterpret_cast<const f16x8*>(&Bb[n * 8192 + kslab]);
    float4 a0 = pa0[kt & 3], a1 = pa1[kt & 3];
    if (kt + 4 < 16) loadA(kt + 4, pa0[kt & 3], pa1[kt & 3]);  // A newest: never drained
    f16x8 af;
    af[0] = (_Float16)a0.x; af[1] = (_Float16)a0.y;
    af[2] = (_Float16)a0.z; af[3] = (_Float16)a0.w;
    af[4] = (_Float16)a1.x; af[5] = (_Float16)a1.y;
    af[6] = (_Float16)a1.z; af[7] = (_Float16)a1.w;
#pragma unroll
    for (int n = 0; n < 8; ++n)
      acc[n] = __builtin_amdgcn_mfma_f32_16x16x32_f16(af, bfr[n], acc[n], 0, 0, 0);
  }

  // epilogue: C(row = kg*4 + q (+w16*16), col = n*16 + lr)
#pragma unroll
  for (int q = 0; q < 4; ++q) {
    int gr = w16 * 16 + kg * 4 + q;
    float dv = dinv[gr];
#pragma unroll
    for (int n = 0; n < 8; ++n) {
      int gc = n * 16 + lr;
      float v = fmaxf(acc[n][q] + bias[gc], 0.f);
      C16u[(size_t)gr * HIDC + gc] = __float2half(v);
      C16s[(size_t)gr * HIDC + gc] = __float2half(v * dv);
    }
  }
}

// ---------------- FUSED layer: 16 waves = 16 nodes, window-sorted via perm ----------------
// EPI 0: relu -> fp16 scaled row-major (feeds next layer)
// EPI 1: last layer: h -> LDS A-frags -> out = h @ W_out + b_out (fp32)

template <int EPI>
__global__ void __launch_bounds__(1024) k_layer(
    const __half* __restrict__ hs, const __half* __restrict__ h0u,
    const __half* __restrict__ Bf,
    const int* __restrict__ row_ptr, const int* __restrict__ deg,
    const int* __restrict__ col, const float* __restrict__ dinv,
    const int* __restrict__ perm,
    __half* __restrict__ Cs,
    const __half* __restrict__ Bf2, const float* __restrict__ bias2,
    float* __restrict__ outp) {
  __shared__ __half zb[16 * 128];   // 4 KB
  int wv = threadIdx.x >> 6, lane = threadIdx.x & 63;
  int g = lane >> 4;    // edge slot within chunk
  int fl = lane & 15;   // feature sub-lane
  int row0 = blockIdx.x * 16;
  int node = perm[row0 + wv];           // within same 256-node window as row0

  // ---- gather: one wave per node; 64-edge super-chunks, shfl-distributed cols ----
  int start = row_ptr[node];
  int cnt = deg[node] + 1;

  float acc[8];
#pragma unroll
  for (int j = 0; j < 8; ++j) acc[j] = 0.f;

  for (int base = 0; base < cnt; base += 64) {
    int rem = cnt - base;
    if (rem > 64) rem = 64;
    int myc = col[start + base + (lane < rem ? lane : 0)];  // 64 indices, one load
    int nch = (rem + 3) >> 2;

    auto get = [&](int ch, s16x8& v, float& m) {
      int e = ch * 4 + g;
      int c = __shfl(myc, e & 63, 64);
      m = (e < rem) ? 1.f : 0.f;
      v = *reinterpret_cast<const s16x8*>(&hs[(size_t)c * HIDC + fl * 8]);
    };

    s16x8 curv; float curm;
    get(0, curv, curm);
    for (int ch = 0; ch < nch; ++ch) {
      s16x8 nv = {}; float nm = 0.f;
      if (ch + 1 < nch) get(ch + 1, nv, nm);
      const __half2* hp = reinterpret_cast<const __half2*>(&curv);
#pragma unroll
      for (int j = 0; j < 4; ++j) {
        float2 f = __half22float2(hp[j]);
        acc[2 * j]     = fmaf(curm, f.x, acc[2 * j]);
        acc[2 * j + 1] = fmaf(curm, f.y, acc[2 * j + 1]);
      }
      curv = nv; curm = nm;
    }
  }

#pragma unroll
  for (int j = 0; j < 8; ++j) {
    acc[j] += __shfl_xor(acc[j], 16, 64);
    acc[j] += __shfl_xor(acc[j], 32, 64);
  }

  if (g == 0) {
    float dr = dinv[node] * 0.9f;
    s16x8 r0 = *reinterpret_cast<const s16x8*>(&h0u[(size_t)node * HIDC + fl * 8]);
    const __half2* r0p = reinterpret_cast<const __half2*>(&r0);
    f16x8 w;
#pragma unroll
    for (int j = 0; j < 4; ++j) {
      float2 f0 = __half22float2(r0p[j]);
      w[2 * j]     = (_Float16)fmaf(dr, acc[2 * j],     0.1f * f0.x);
      w[2 * j + 1] = (_Float16)fmaf(dr, acc[2 * j + 1], 0.1f * f0.y);
    }
    *reinterpret_cast<f16x8*>(&zb[wv * 128 + ((fl * 8) ^ ((wv & 7) << 3))]) = w;
  }
  __syncthreads();

  // ---- GEMM1: 16 x 128, K = 128; wave n (n<8) computes column-frag n ----
  int lr = lane & 15, kg = lane >> 4;
  f32x4 c = {0.f, 0.f, 0.f, 0.f};
  if (wv < 8) {
    const __half* Bb = Bf + wv * 2048 + kg * 128 + lr * 8;
#pragma unroll
    for (int kt = 0; kt < 4; ++kt) {
      f16x8 a = *reinterpret_cast<const f16x8*>(
          &zb[lr * 128 + ((kt * 32 + kg * 8) ^ ((lr & 7) << 3))]);
      f16x8 b = *reinterpret_cast<const f16x8*>(Bb + kt * 512);
      c = __builtin_amdgcn_mfma_f32_16x16x32_f16(a, b, c, 0, 0, 0);
    }
  }

  if (EPI == 0) {
    if (wv < 8) {
      int gc = wv * 16 + lr;
#pragma unroll
      for (int q = 0; q < 4; ++q) {
        int pr = perm[row0 + kg * 4 + q];   // row within the 256-node window
        float v = fmaxf(c[q], 0.f);
        Cs[(size_t)pr * HIDC + gc] = __float2half(v * dinv[pr]);
      }
    }
  } else {
    // ---- last layer: h -> LDS A-frags, then out = h @ W_out + b_out ----
    __syncthreads();   // all GEMM1 zb reads complete
    if (wv < 8) {
      int gc = wv * 16 + lr;   // k index of h
#pragma unroll
      for (int q = 0; q < 4; ++q) {
        int r = kg * 4 + q;
        zb[(gc >> 3) * 128 + r * 8 + (gc & 7)] = __float2half(fmaxf(c[q], 0.f));
      }
    }
    __syncthreads();
    if (wv < 4) {
      f32x4 o = {0.f, 0.f, 0.f, 0.f};
      const __half* Bb2 = Bf2 + wv * 2048 + kg * 128 + lr * 8;
#pragma unroll
      for (int kt = 0; kt < 4; ++kt) {
        f16x8 a = *reinterpret_cast<const f16x8*>(&zb[(kt * 4 + kg) * 128 + lr * 8]);
        f16x8 b = *reinterpret_cast<const f16x8*>(Bb2 + kt * 512);
        o = __builtin_amdgcn_mfma_f32_16x16x32_f16(a, b, o, 0, 0, 0);
      }
      int gc = wv * 16 + lr;
      float bv = bias2[gc];
#pragma unroll
      for (int q = 0; q < 4; ++q) {
        int pr = perm[row0 + kg * 4 + q];
        outp[(size_t)pr * OUTC + gc] = o[q] + bv;
      }
    }
  }
}

// ---------------- launch ----------------

extern "C" void kernel_launch(void* const* d_in, const int* in_sizes, int n_in,
                              void* d_out, int out_size, void* d_ws, size_t ws_size,
                              hipStream_t stream) {
  const float* x     = (const float*)d_in[0];
  const int*   ei    = (const int*)d_in[1];
  const float* W_in  = (const float*)d_in[2];
  const float* b_in  = (const float*)d_in[3];
  const float* W_cv  = (const float*)d_in[4];
  const float* W_out = (const float*)d_in[5];
  const float* b_out = (const float*)d_in[6];
  float* out = (float*)d_out;

  char* ws = (char*)d_ws;
  size_t off = 0;
  auto alloc = [&](size_t bytes) {
    char* p = ws + off;
    off = (off + bytes + 255) & ~(size_t)255;
    return p;
  };
  int*    deg     = (int*)alloc((size_t)NN * 4);
  int*    row_ptr = (int*)alloc((size_t)NN * 4);
  int*    cursor  = (int*)alloc((size_t)NN * 4);
  int*    bsum    = (int*)alloc(512 * 4);
  int*    perm    = (int*)alloc((size_t)PERMSZ * 4);
  float*  dinv    = (float*)alloc((size_t)NN * 4);
  int*    col     = (int*)alloc((size_t)(EE + NN) * 4);
  __half* h016u   = (__half*)alloc((size_t)NN * HIDC * 2);
  __half* h016s   = (__half*)alloc((size_t)NN * HIDC * 2);
  __half* hsA     = (__half*)alloc((size_t)NN * HIDC * 2);
  __half* hsB     = (__half*)alloc((size_t)NN * HIDC * 2);
  __half* wcv16   = (__half*)alloc((size_t)NLAYER * HIDC * HIDC * 2);
  __half* wout16  = (__half*)alloc((size_t)OUTC * HIDC * 2);
  __half* win16   = (__half*)alloc((size_t)HIDC * 512 * 2);

  const int* srcp = ei;
  const int* dstp = ei + EE;

  hipMemsetAsync(deg, 0, (size_t)NN * 4, stream);

  // weight prep
  k_prep_wfin16<<<(HIDC * 512 + 255) / 256, 256, 0, stream>>>(W_in, win16);
  for (int l = 0; l < NLAYER; ++l) {
    float beta = logf(0.5f / (float)(l + 1) + 1.0f);
    k_prep_wf16<<<(HIDC * HIDC + 255) / 256, 256, 0, stream>>>(
        W_cv + (size_t)l * HIDC * HIDC, wcv16 + (size_t)l * HIDC * HIDC,
        HIDC, HIDC, 1.0f - beta, beta);
  }
  k_prep_wf16<<<(OUTC * HIDC + 255) / 256, 256, 0, stream>>>(W_out, wout16, HIDC, OUTC,
                                                             0.f, 1.f);

  // XCD-bucketed degree count
  k_count_x<<<CNT_BLKS, 256, 0, stream>>>(dstp, deg);

  k_scan_block_sums<<<NBLK, 256, 0, stream>>>(deg, bsum, NN);
  k_scan_partials<<<1, 512, 0, stream>>>(bsum, NBLK);
  k_scan_final<<<NBLK, 256, 0, stream>>>(deg, bsum, row_ptr, NN);
  k_init_rows<<<(NN + 255) / 256, 256, 0, stream>>>(deg, row_ptr, cursor, col, dinv, NN);

  // per-window degree sort (deterministic, no atomics)
  k_sort_win<<<NBLK, 256, 0, stream>>>(deg, perm);

  // XCD-bucketed CSR fill
  k_fill_x<<<CNT_BLKS, 256, 0, stream>>>(srcp, dstp, cursor, col);

  // h0 = relu(x @ W_in + b_in) (fp16 MFMA, barrier-free, B-first prefetch order)
  k_gemm_in<<<(NB16 + 3) / 4, 256, 0, stream>>>(x, win16, b_in, h016u, h016s, dinv);

  const __half* hcur = h016s;
  for (int l = 0; l < NLAYER; ++l) {
    const __half* wl = wcv16 + (size_t)l * HIDC * HIDC;
    if (l < NLAYER - 1) {
      __half* tgt = (l & 1) ? hsB : hsA;
      k_layer<0><<<NB16, 1024, 0, stream>>>(hcur, h016u, wl, row_ptr, deg, col, dinv,
                                            perm, tgt, nullptr, nullptr, nullptr);
      hcur = tgt;
    } else {
      k_layer<1><<<NB16, 1024, 0, stream>>>(hcur, h016u, wl, row_ptr, deg, col, dinv,
                                            perm, nullptr, wout16, b_out, out);
    }
  }
}

// Round 18
// 890.511 us; speedup vs baseline: 1.1579x; 1.1579x over previous
//
#include <hip/hip_runtime.h>
#include <hip/hip_fp16.h>
#include <cmath>

#define NN 100000
#define EE 1600000
#define INC 500
#define HIDC 128
#define OUTC 64
#define NLAYER 8
#define NB16 6250           // NN / 16 exactly
#define NPX 12500           // NN / 8 (nodes per XCD bucket)
#define CNT_BLKS 50000      // 6250 chunks * 8 buckets
#define NBLK 391            // ceil(NN/256)
#define GEMM_BLKS 782       // ceil(NN/128)

typedef float f32x4 __attribute__((ext_vector_type(4)));
typedef _Float16 f16x8 __attribute__((ext_vector_type(8)));
typedef _Float16 f16x4 __attribute__((ext_vector_type(4)));
typedef short s16x8 __attribute__((ext_vector_type(8)));

// frag layout addr for (row, k), K pitch Kp: [(row/16)][k/8][row%16][k%8]
__device__ __forceinline__ int fraddr(int row, int k, int Kp) {
  return (row >> 4) * (Kp * 16) + (k >> 3) * 128 + (row & 15) * 8 + (k & 7);
}

// ---------------- graph preprocessing ----------------

// XCD-bucketed degree count: block's XCD (bid%8) == dst bucket
__global__ void __launch_bounds__(256) k_count_x(
    const int* __restrict__ dst, int* __restrict__ deg) {
  int chunk = blockIdx.x >> 3;
  int xcd = blockIdx.x & 7;
  int e = chunk * 256 + threadIdx.x;   // EE == 6250*256 exactly
  int d = dst[e];
  if (d / NPX == xcd) atomicAdd(&deg[d], 1);
}

__global__ void k_scan_block_sums(const int* __restrict__ deg, int* __restrict__ bsum, int n) {
  __shared__ int sm[256];
  int i = blockIdx.x * 256 + threadIdx.x;
  int v = (i < n) ? deg[i] + 1 : 0;  // +1 for self-loop
  sm[threadIdx.x] = v;
  __syncthreads();
  for (int s = 128; s > 0; s >>= 1) {
    if (threadIdx.x < s) sm[threadIdx.x] += sm[threadIdx.x + s];
    __syncthreads();
  }
  if (threadIdx.x == 0) bsum[blockIdx.x] = sm[0];
}

__global__ void k_scan_partials(int* __restrict__ bsum, int nb) {
  __shared__ int sm[512];
  int t = threadIdx.x;
  sm[t] = (t < nb) ? bsum[t] : 0;
  __syncthreads();
  for (int s = 1; s < 512; s <<= 1) {
    int v = (t >= s) ? sm[t - s] : 0;
    __syncthreads();
    sm[t] += v;
    __syncthreads();
  }
  if (t < nb) bsum[t] = (t == 0) ? 0 : sm[t - 1];  // exclusive
}

__global__ void k_scan_final(const int* __restrict__ deg, const int* __restrict__ bsum,
                             int* __restrict__ row_ptr, int n) {
  __shared__ int sm[256];
  int i = blockIdx.x * 256 + threadIdx.x;
  int v = (i < n) ? deg[i] + 1 : 0;
  sm[threadIdx.x] = v;
  __syncthreads();
  for (int s = 1; s < 256; s <<= 1) {
    int u = (threadIdx.x >= s) ? sm[threadIdx.x - s] : 0;
    __syncthreads();
    sm[threadIdx.x] += u;
    __syncthreads();
  }
  if (i < n) row_ptr[i] = bsum[blockIdx.x] + sm[threadIdx.x] - v;  // exclusive
}

__global__ void k_init_rows(const int* __restrict__ deg, const int* __restrict__ row_ptr,
                            int* __restrict__ cursor, int* __restrict__ col,
                            float* __restrict__ dinv, int n) {
  int i = blockIdx.x * blockDim.x + threadIdx.x;
  if (i < n) {
    int rp = row_ptr[i];
    col[rp] = i;          // self-loop entry first (deterministic)
    cursor[i] = rp + 1;
    dinv[i] = rsqrtf((float)(deg[i] + 1));
  }
}

// XCD-bucketed CSR fill
__global__ void __launch_bounds__(256) k_fill_x(
    const int* __restrict__ src, const int* __restrict__ dst,
    int* __restrict__ cursor, int* __restrict__ col) {
  int chunk = blockIdx.x >> 3;
  int xcd = blockIdx.x & 7;
  int e = chunk * 256 + threadIdx.x;   // EE == 6250*256 exactly
  int d = dst[e];
  if (d / NPX == xcd) {
    int pos = atomicAdd(&cursor[d], 1);
    col[pos] = src[e];
  }
}

// ---- W_in -> fp16 fragment layout, Kp=512 (zero-padded K>=500) ----

__global__ void k_prep_wfin16(const float* __restrict__ W, __half* __restrict__ f) {
  int i = blockIdx.x * 256 + threadIdx.x;
  if (i >= HIDC * 512) return;
  int n = i / 512, k = i % 512;
  float v = (k < INC) ? W[(size_t)k * HIDC + n] : 0.f;
  f[fraddr(n, k, 512)] = __float2half(v);
}

// ---- W -> fp16 fragment layout, optional identity fold: M = idc*I + ws*W ----

__global__ void k_prep_wf16(const float* __restrict__ W, __half* __restrict__ f,
                            int K, int N, float idc, float ws) {
  int i = blockIdx.x * 256 + threadIdx.x;
  if (i >= N * K) return;
  int n = i / K, k = i % K;
  float v = ws * W[(size_t)k * N + n] + ((k == n) ? idc : 0.f);
  f[fraddr(n, k, K)] = __float2half(v);
}

// ---------------- fp16 input GEMM, LDS-staged 128-tile (round-14 best: 124 us) ----------------

__global__ void __launch_bounds__(256) k_gemm_in(
    const float* __restrict__ A, const __half* __restrict__ Bf,
    const float* __restrict__ bias,
    __half* __restrict__ C16u, __half* __restrict__ C16s,
    const float* __restrict__ dinv) {
  __shared__ __align__(16) _Float16 Ax[128 * 40];   // 10 KB
  int tid = threadIdx.x;
  int wid = tid >> 6, lane = tid & 63;
  int wr = wid >> 1, wc = wid & 1;
  int lr = lane & 15, kg = lane >> 4;
  int row0 = blockIdx.x * 128;

  f32x4 acc[4][4];
#pragma unroll
  for (int m = 0; m < 4; ++m)
#pragma unroll
    for (int n = 0; n < 4; ++n) acc[m][n] = {0.f, 0.f, 0.f, 0.f};

  float4 va[4];
  auto issue_loads = [&](int kt) {
#pragma unroll
    for (int p = 0; p < 4; ++p) {
      int idx = tid + p * 256;
      int r = idx >> 3, kq = idx & 7;
      int gr = row0 + r, gk = kt + kq * 4;
      va[p] = make_float4(0.f, 0.f, 0.f, 0.f);
      if (gr < NN && gk < INC) va[p] = *reinterpret_cast<const float4*>(&A[(size_t)gr * INC + gk]);
    }
  };

  issue_loads(0);
  for (int kt = 0; kt < 512; kt += 32) {
#pragma unroll
    for (int p = 0; p < 4; ++p) {
      int idx = tid + p * 256;
      int r = idx >> 3, kq = idx & 7;
      const float* vp = &va[p].x;
      f16x4 h4;
#pragma unroll
      for (int e = 0; e < 4; ++e) h4[e] = (_Float16)vp[e];
      *reinterpret_cast<f16x4*>(&Ax[r * 40 + kq * 4]) = h4;
    }
    __syncthreads();
    if (kt + 32 < 512) issue_loads(kt + 32);  // overlaps MFMA below

    f16x8 af[4];
#pragma unroll
    for (int m = 0; m < 4; ++m) {
      int r = wr * 64 + m * 16 + lr;
      af[m] = *reinterpret_cast<const f16x8*>(&Ax[r * 40 + kg * 8]);
    }
#pragma unroll
    for (int n = 0; n < 4; ++n) {
      size_t bb = (size_t)(wc * 4 + n) * 8192 + (size_t)(kt / 8 + kg) * 128 + lr * 8;
      f16x8 b = *reinterpret_cast<const f16x8*>(&Bf[bb]);
#pragma unroll
      for (int m = 0; m < 4; ++m)
        acc[m][n] = __builtin_amdgcn_mfma_f32_16x16x32_f16(af[m], b, acc[m][n], 0, 0, 0);
    }
    __syncthreads();
  }

#pragma unroll
  for (int m = 0; m < 4; ++m) {
#pragma unroll
    for (int n = 0; n < 4; ++n) {
      int gc = wc * 64 + n * 16 + lr;
#pragma unroll
      for (int q = 0; q < 4; ++q) {
        int gr = row0 + wr * 64 + m * 16 + kg * 4 + q;
        if (gr < NN) {
          float v = fmaxf(acc[m][n][q] + bias[gc], 0.f);
          C16u[(size_t)gr * HIDC + gc] = __float2half(v);
          C16s[(size_t)gr * HIDC + gc] = __float2half(v * dinv[gr]);
        }
      }
    }
  }
}

// ---------------- FUSED layer: 16 waves = 16 nodes (identity order) ----------------
// EPI 0: relu -> fp16 scaled row-major (feeds next layer)
// EPI 1: last layer: h -> LDS A-frags -> out = h @ W_out + b_out (fp32)

template <int EPI>
__global__ void __launch_bounds__(1024) k_layer(
    const __half* __restrict__ hs, const __half* __restrict__ h0u,
    const __half* __restrict__ Bf,
    const int* __restrict__ row_ptr, const int* __restrict__ deg,
    const int* __restrict__ col, const float* __restrict__ dinv,
    __half* __restrict__ Cs,
    const __half* __restrict__ Bf2, const float* __restrict__ bias2,
    float* __restrict__ outp) {
  __shared__ __half zb[16 * 128];   // 4 KB
  int wv = threadIdx.x >> 6, lane = threadIdx.x & 63;
  int g = lane >> 4;    // edge slot within chunk
  int fl = lane & 15;   // feature sub-lane
  int row0 = blockIdx.x * 16;
  int node = row0 + wv;                 // NN == 6250*16 exactly

  // ---- gather: one wave per node; 64-edge super-chunks, shfl-distributed cols ----
  int start = row_ptr[node];
  int cnt = deg[node] + 1;

  float acc[8];
#pragma unroll
  for (int j = 0; j < 8; ++j) acc[j] = 0.f;

  for (int base = 0; base < cnt; base += 64) {
    int rem = cnt - base;
    if (rem > 64) rem = 64;
    int myc = col[start + base + (lane < rem ? lane : 0)];  // 64 indices, one load
    int nch = (rem + 3) >> 2;

    auto get = [&](int ch, s16x8& v, float& m) {
      int e = ch * 4 + g;
      int c = __shfl(myc, e & 63, 64);
      m = (e < rem) ? 1.f : 0.f;
      v = *reinterpret_cast<const s16x8*>(&hs[(size_t)c * HIDC + fl * 8]);
    };

    s16x8 curv; float curm;
    get(0, curv, curm);
    for (int ch = 0; ch < nch; ++ch) {
      s16x8 nv = {}; float nm = 0.f;
      if (ch + 1 < nch) get(ch + 1, nv, nm);
      const __half2* hp = reinterpret_cast<const __half2*>(&curv);
#pragma unroll
      for (int j = 0; j < 4; ++j) {
        float2 f = __half22float2(hp[j]);
        acc[2 * j]     = fmaf(curm, f.x, acc[2 * j]);
        acc[2 * j + 1] = fmaf(curm, f.y, acc[2 * j + 1]);
      }
      curv = nv; curm = nm;
    }
  }

#pragma unroll
  for (int j = 0; j < 8; ++j) {
    acc[j] += __shfl_xor(acc[j], 16, 64);
    acc[j] += __shfl_xor(acc[j], 32, 64);
  }

  if (g == 0) {
    float dr = dinv[node] * 0.9f;
    s16x8 r0 = *reinterpret_cast<const s16x8*>(&h0u[(size_t)node * HIDC + fl * 8]);
    const __half2* r0p = reinterpret_cast<const __half2*>(&r0);
    f16x8 w;
#pragma unroll
    for (int j = 0; j < 4; ++j) {
      float2 f0 = __half22float2(r0p[j]);
      w[2 * j]     = (_Float16)fmaf(dr, acc[2 * j],     0.1f * f0.x);
      w[2 * j + 1] = (_Float16)fmaf(dr, acc[2 * j + 1], 0.1f * f0.y);
    }
    *reinterpret_cast<f16x8*>(&zb[wv * 128 + ((fl * 8) ^ ((wv & 7) << 3))]) = w;
  }
  __syncthreads();

  // ---- GEMM1: 16 x 128, K = 128; wave n (n<8) computes column-frag n ----
  int lr = lane & 15, kg = lane >> 4;
  f32x4 c = {0.f, 0.f, 0.f, 0.f};
  if (wv < 8) {
    const __half* Bb = Bf + wv * 2048 + kg * 128 + lr * 8;
#pragma unroll
    for (int kt = 0; kt < 4; ++kt) {
      f16x8 a = *reinterpret_cast<const f16x8*>(
          &zb[lr * 128 + ((kt * 32 + kg * 8) ^ ((lr & 7) << 3))]);
      f16x8 b = *reinterpret_cast<const f16x8*>(Bb + kt * 512);
      c = __builtin_amdgcn_mfma_f32_16x16x32_f16(a, b, c, 0, 0, 0);
    }
  }

  if (EPI == 0) {
    if (wv < 8) {
      int gc = wv * 16 + lr;
#pragma unroll
      for (int q = 0; q < 4; ++q) {
        int gr = row0 + kg * 4 + q;
        float v = fmaxf(c[q], 0.f);
        Cs[(size_t)gr * HIDC + gc] = __float2half(v * dinv[gr]);
      }
    }
  } else {
    // ---- last layer: h -> LDS A-frags, then out = h @ W_out + b_out ----
    __syncthreads();   // all GEMM1 zb reads complete
    if (wv < 8) {
      int gc = wv * 16 + lr;   // k index of h
#pragma unroll
      for (int q = 0; q < 4; ++q) {
        int r = kg * 4 + q;
        zb[(gc >> 3) * 128 + r * 8 + (gc & 7)] = __float2half(fmaxf(c[q], 0.f));
      }
    }
    __syncthreads();
    if (wv < 4) {
      f32x4 o = {0.f, 0.f, 0.f, 0.f};
      const __half* Bb2 = Bf2 + wv * 2048 + kg * 128 + lr * 8;
#pragma unroll
      for (int kt = 0; kt < 4; ++kt) {
        f16x8 a = *reinterpret_cast<const f16x8*>(&zb[(kt * 4 + kg) * 128 + lr * 8]);
        f16x8 b = *reinterpret_cast<const f16x8*>(Bb2 + kt * 512);
        o = __builtin_amdgcn_mfma_f32_16x16x32_f16(a, b, o, 0, 0, 0);
      }
      int gc = wv * 16 + lr;
      float bv = bias2[gc];
#pragma unroll
      for (int q = 0; q < 4; ++q) {
        int gr = row0 + kg * 4 + q;
        outp[(size_t)gr * OUTC + gc] = o[q] + bv;
      }
    }
  }
}

// ---------------- launch ----------------

extern "C" void kernel_launch(void* const* d_in, const int* in_sizes, int n_in,
                              void* d_out, int out_size, void* d_ws, size_t ws_size,
                              hipStream_t stream) {
  const float* x     = (const float*)d_in[0];
  const int*   ei    = (const int*)d_in[1];
  const float* W_in  = (const float*)d_in[2];
  const float* b_in  = (const float*)d_in[3];
  const float* W_cv  = (const float*)d_in[4];
  const float* W_out = (const float*)d_in[5];
  const float* b_out = (const float*)d_in[6];
  float* out = (float*)d_out;

  char* ws = (char*)d_ws;
  size_t off = 0;
  auto alloc = [&](size_t bytes) {
    char* p = ws + off;
    off = (off + bytes + 255) & ~(size_t)255;
    return p;
  };
  int*    deg     = (int*)alloc((size_t)NN * 4);
  int*    row_ptr = (int*)alloc((size_t)NN * 4);
  int*    cursor  = (int*)alloc((size_t)NN * 4);
  int*    bsum    = (int*)alloc(512 * 4);
  float*  dinv    = (float*)alloc((size_t)NN * 4);
  int*    col     = (int*)alloc((size_t)(EE + NN) * 4);
  __half* h016u   = (__half*)alloc((size_t)NN * HIDC * 2);
  __half* h016s   = (__half*)alloc((size_t)NN * HIDC * 2);
  __half* hsA     = (__half*)alloc((size_t)NN * HIDC * 2);
  __half* hsB     = (__half*)alloc((size_t)NN * HIDC * 2);
  __half* wcv16   = (__half*)alloc((size_t)NLAYER * HIDC * HIDC * 2);
  __half* wout16  = (__half*)alloc((size_t)OUTC * HIDC * 2);
  __half* win16   = (__half*)alloc((size_t)HIDC * 512 * 2);

  const int* srcp = ei;
  const int* dstp = ei + EE;

  hipMemsetAsync(deg, 0, (size_t)NN * 4, stream);

  // weight prep
  k_prep_wfin16<<<(HIDC * 512 + 255) / 256, 256, 0, stream>>>(W_in, win16);
  for (int l = 0; l < NLAYER; ++l) {
    float beta = logf(0.5f / (float)(l + 1) + 1.0f);
    k_prep_wf16<<<(HIDC * HIDC + 255) / 256, 256, 0, stream>>>(
        W_cv + (size_t)l * HIDC * HIDC, wcv16 + (size_t)l * HIDC * HIDC,
        HIDC, HIDC, 1.0f - beta, beta);
  }
  k_prep_wf16<<<(OUTC * HIDC + 255) / 256, 256, 0, stream>>>(W_out, wout16, HIDC, OUTC,
                                                             0.f, 1.f);

  // XCD-bucketed degree count
  k_count_x<<<CNT_BLKS, 256, 0, stream>>>(dstp, deg);

  k_scan_block_sums<<<NBLK, 256, 0, stream>>>(deg, bsum, NN);
  k_scan_partials<<<1, 512, 0, stream>>>(bsum, NBLK);
  k_scan_final<<<NBLK, 256, 0, stream>>>(deg, bsum, row_ptr, NN);
  k_init_rows<<<(NN + 255) / 256, 256, 0, stream>>>(deg, row_ptr, cursor, col, dinv, NN);

  // XCD-bucketed CSR fill
  k_fill_x<<<CNT_BLKS, 256, 0, stream>>>(srcp, dstp, cursor, col);

  // h0 = relu(x @ W_in + b_in) (fp16 MFMA, LDS-staged)
  k_gemm_in<<<GEMM_BLKS, 256, 0, stream>>>(x, win16, b_in, h016u, h016s, dinv);

  const __half* hcur = h016s;
  for (int l = 0; l < NLAYER; ++l) {
    const __half* wl = wcv16 + (size_t)l * HIDC * HIDC;
    if (l < NLAYER - 1) {
      __half* tgt = (l & 1) ? hsB : hsA;
      k_layer<0><<<NB16, 1024, 0, stream>>>(hcur, h016u, wl, row_ptr, deg, col, dinv,
                                            tgt, nullptr, nullptr, nullptr);
      hcur = tgt;
    } else {
      k_layer<1><<<NB16, 1024, 0, stream>>>(hcur, h016u, wl, row_ptr, deg, col, dinv,
                                            nullptr, wout16, b_out, out);
    }
  }
}